// Round 1
// 105.760 us; speedup vs baseline: 1.0632x; 1.0632x over previous
//
#include <hip/hip_runtime.h>

// Problem constants (GATLayer): B=4, N=2048, TOKEN_DIM=512, HIDDEN=128
// IO dtype: fp32. Internally: bf16 MFMA with fp32 accumulate.
// v8: three dispatches.
//   k_prep : fc_w fp32 -> bf16 (RTNE) ONCE into workspace (was converted
//            redundantly by all 512 k_fused blocks = 33.5M f2bf ops).
//   k_fused: FC(MFMA, B-frags now direct bf16 loads) + bias + LN + scores
//            + transposed hT.
//   k_attn : unchanged from v7 (double-buffered P staging, one barrier/chunk).
// All fp32->bf16 via manual RTNE f2bf (validated in passing runs).
#define NB      4
#define NTOK    2048
#define TOKDIM  512
#define HID     128
#define NROWS   (NB * NTOK)      // 8192
#define LN_EPS  1e-5f
#define NEG_SLOPE 0.01f

typedef short bf16x8 __attribute__((ext_vector_type(8)));   // 8 bf16 in 4 VGPRs
typedef float f32x4  __attribute__((ext_vector_type(4)));

static __device__ __forceinline__ unsigned short f2bf(float f) {
    union { float f; unsigned int i; } v; v.f = f;
    unsigned int i = v.i;
    i += 0x7FFFu + ((i >> 16) & 1u);   // round-to-nearest-even
    return (unsigned short)(i >> 16);
}

// ---------------------------------------------------------------------------
// k_prep: convert fc_w (128x512 fp32) -> bf16 once. 64 blocks x 256 thr,
// 4 elems/thread (float4 load -> ushort4 store). Numerics identical to the
// inline cvt8 path it replaces (same RTNE f2bf).
// ---------------------------------------------------------------------------
__global__ __launch_bounds__(256) void k_prep(const float* __restrict__ W,
                                              unsigned short* __restrict__ Wb) {
    const int g = blockIdx.x * 256 + threadIdx.x;   // 0..16383
    float4 v = *(const float4*)(W + (size_t)g * 4);
    ushort4 o;
    o.x = f2bf(v.x); o.y = f2bf(v.y); o.z = f2bf(v.z); o.w = f2bf(v.w);
    *(ushort4*)(Wb + (size_t)g * 4) = o;
}

// ---------------------------------------------------------------------------
// k_fused: per 16-row tile: FC (MFMA, A from LDS-staged bf16 X, B from
// pre-converted bf16 W) + bias + LayerNorm + scores + transposed hT write.
// Grid 512 blocks x 512 thr (8 waves). Wave wv owns n-cols [wv*16,+16).
// ---------------------------------------------------------------------------
__global__ __launch_bounds__(512) void k_fused(const float* __restrict__ X,
                                               const unsigned short* __restrict__ Wb,
                                               const float* __restrict__ fcb,
                                               const float* __restrict__ attnw,
                                               const float* __restrict__ attnb,
                                               const float* __restrict__ lng,
                                               const float* __restrict__ lnb,
                                               unsigned short* __restrict__ hT,
                                               float* __restrict__ srow,
                                               float* __restrict__ cc) {
    __shared__ char smem[16640 + 16 * 132 * 4];
    unsigned short* ldsX = (unsigned short*)smem;            // [16][520]
    unsigned short* ldsT = (unsigned short*)smem;            // [128][20] (reuse)
    float* hfull = (float*)(smem + 16640);                   // [16][132]

    const int tid  = threadIdx.x;
    const int wv   = tid >> 6;
    const int lane = tid & 63;
    const int m    = lane & 15;
    const int q    = lane >> 4;
    const int rowbase = blockIdx.x * 16;
    const int nbase   = wv * 16;

    // ---- phase A: stage X tile -> LDS bf16 (each element converted once)
    {
        const int r  = tid >> 5;            // 0..15
        const int c0 = (tid & 31) * 16;     // 0..496
        const float* xp = X + (size_t)(rowbase + r) * TOKDIM + c0;
        bf16x8 v0, v1;
#pragma unroll
        for (int u = 0; u < 8; ++u) v0[u] = (short)f2bf(xp[u]);
#pragma unroll
        for (int u = 0; u < 8; ++u) v1[u] = (short)f2bf(xp[8 + u]);
        *(bf16x8*)&ldsX[r * 520 + c0]     = v0;
        *(bf16x8*)&ldsX[r * 520 + c0 + 8] = v1;
    }
    __syncthreads();

    // ---- phase B: MFMA. A[m][k] from ldsX, B[k][n]=W[n][k] direct bf16.
    const unsigned short* wp = Wb + (size_t)(nbase + m) * TOKDIM + q * 8;
    f32x4 acc = {0.f, 0.f, 0.f, 0.f};
#pragma unroll
    for (int kk = 0; kk < TOKDIM / 32; ++kk) {
        bf16x8 a = *(const bf16x8*)&ldsX[m * 520 + kk * 32 + q * 8];
        bf16x8 b = *(const bf16x8*)(wp + kk * 32);
        acc = __builtin_amdgcn_mfma_f32_16x16x32_bf16(a, b, acc, 0, 0, 0);
    }

    // ---- phase C: acc (+fc_b) -> hfull LDS
    {
        const float bias = fcb[nbase + m];
#pragma unroll
        for (int r = 0; r < 4; ++r)
            hfull[(q * 4 + r) * 132 + nbase + m] = acc[r] + bias;
    }
    __syncthreads();   // hfull ready; ldsX dead (safe to reuse as ldsT)

    // ---- phase D: LN + scores; write bf16 h into ldsT transposed
    {
        const int r   = tid >> 5;           // row 0..15
        const int l32 = tid & 31;
        const int c0  = l32 * 4;
        float4 hv = *(const float4*)&hfull[r * 132 + c0];
        float v[4] = {hv.x, hv.y, hv.z, hv.w};

        float s  = v[0] + v[1] + v[2] + v[3];
        float ss = v[0]*v[0] + v[1]*v[1] + v[2]*v[2] + v[3]*v[3];
#pragma unroll
        for (int d = 1; d < 32; d <<= 1) {
            s  += __shfl_xor(s,  d, 64);
            ss += __shfl_xor(ss, d, 64);
        }
        float mu  = s * (1.f / HID);
        float var = ss * (1.f / HID) - mu * mu;
        float rs  = rsqrtf(var + LN_EPS);

        float n[4], sr = 0.f, sc = 0.f;
#pragma unroll
        for (int k = 0; k < 4; ++k) {
            n[k] = lng[c0 + k] * (v[k] - mu) * rs + lnb[c0 + k];
            sr += n[k] * attnw[c0 + k];
            sc += n[k] * attnw[HID + c0 + k];
            ldsT[(c0 + k) * 20 + r] = f2bf(n[k]);
        }
#pragma unroll
        for (int d = 1; d < 32; d <<= 1) {
            sr += __shfl_xor(sr, d, 64);
            sc += __shfl_xor(sc, d, 64);
        }
        if (l32 == 0) {
            int grow = rowbase + r;
            srow[grow] = sr;
            cc[grow]   = sc + attnb[0];
        }
    }
    __syncthreads();

    // ---- phase E: coalesced hT write. thread t: d = t>>2, 4 j's.
    {
        const int d  = tid >> 2;
        const int j4 = (tid & 3) * 4;
        const int b    = blockIdx.x >> 7;          // 128 blocks per batch
        const int jblk = (blockIdx.x & 127) * 16;
        ushort4 o;
        o.x = ldsT[d * 20 + j4 + 0];
        o.y = ldsT[d * 20 + j4 + 1];
        o.z = ldsT[d * 20 + j4 + 2];
        o.w = ldsT[d * 20 + j4 + 3];
        *(ushort4*)(hT + ((size_t)(b * HID + d)) * NTOK + jblk + j4) = o;
    }
}

// ---------------------------------------------------------------------------
// k_attn v6 (unchanged): 256 blocks x 512 thr (8 waves); block owns 32 i-rows;
// j in 8 chunks of 256. pP double-buffered -> ONE barrier per chunk; next
// chunk's srow + B-frags prefetched into registers before the barrier.
// ---------------------------------------------------------------------------
__global__ __launch_bounds__(512) void k_attn(const unsigned short* __restrict__ hT,
                                              const float* __restrict__ srow,
                                              const float* __restrict__ cc,
                                              float* __restrict__ out) {
    __shared__ unsigned short pP[2][32][264];   // 2 x 16896 B, +8 pad
    __shared__ float pDen[32][16];              // 2 KB
    __shared__ float denv[32];

    const int tid  = threadIdx.x;
    const int wv   = tid >> 6;
    const int lane = tid & 63;
    const int m    = lane & 15;
    const int q    = lane >> 4;
    const int rowbase = blockIdx.x * 32;     // global row base
    const int b    = blockIdx.x >> 6;        // 64 blocks per batch
    const int dbase = wv * 16;

    // producer indices
    const int i_loc = tid >> 4;              // 0..31
    const int jseg  = (tid & 15) * 16;       // 0..240
    const float ci  = cc[rowbase + i_loc];
    const float* sp = srow + (size_t)b * NTOK + jseg;

    // consumer B pointer
    const unsigned short* hp =
        hT + ((size_t)(b * HID + dbase + m)) * NTOK + q * 8;

    f32x4 acc0 = {0.f, 0.f, 0.f, 0.f};      // i-subtile 0 (rows 0..15)
    f32x4 acc1 = {0.f, 0.f, 0.f, 0.f};      // i-subtile 1 (rows 16..31)
    float lsum = 0.f;

    // ---- prefetch chunk 0
    float4 s0 = *(const float4*)(sp);
    float4 s1 = *(const float4*)(sp + 4);
    float4 s2 = *(const float4*)(sp + 8);
    float4 s3 = *(const float4*)(sp + 12);
    bf16x8 bcur[8], bnxt[8];
#pragma unroll
    for (int s = 0; s < 8; ++s) bcur[s] = *(const bf16x8*)(hp + s * 32);

#pragma unroll
    for (int ch = 0; ch < 8; ++ch) {
        // ---- produce chunk ch from prefetched srow values
        {
            float sv[16] = {s0.x, s0.y, s0.z, s0.w, s1.x, s1.y, s1.z, s1.w,
                            s2.x, s2.y, s2.z, s2.w, s3.x, s3.y, s3.z, s3.w};
            bf16x8 v0, v1;
#pragma unroll
            for (int u = 0; u < 8; ++u) {
                float z = ci + sv[u];
                z = fmaxf(z, NEG_SLOPE * z);
                float p = __expf(z);
                lsum += p;
                v0[u] = (short)f2bf(p);
            }
#pragma unroll
            for (int u = 0; u < 8; ++u) {
                float z = ci + sv[8 + u];
                z = fmaxf(z, NEG_SLOPE * z);
                float p = __expf(z);
                lsum += p;
                v1[u] = (short)f2bf(p);
            }
            *(bf16x8*)&pP[ch & 1][i_loc][jseg]     = v0;
            *(bf16x8*)&pP[ch & 1][i_loc][jseg + 8] = v1;
        }

        // ---- prefetch chunk ch+1 (overlaps with barrier + consume below)
        if (ch < 7) {
            const float* spn = sp + (ch + 1) * 256;
            s0 = *(const float4*)(spn);
            s1 = *(const float4*)(spn + 4);
            s2 = *(const float4*)(spn + 8);
            s3 = *(const float4*)(spn + 12);
            const unsigned short* hpn = hp + (ch + 1) * 256;
#pragma unroll
            for (int s = 0; s < 8; ++s) bnxt[s] = *(const bf16x8*)(hpn + s * 32);
        }

        __syncthreads();   // pP[ch&1] ready for all threads

        // ---- consume chunk ch: 8 k-steps, B-frag reused by both i-subtiles
#pragma unroll
        for (int s = 0; s < 8; ++s) {
            bf16x8 a0 = *(const bf16x8*)&pP[ch & 1][m][s * 32 + q * 8];
            bf16x8 a1 = *(const bf16x8*)&pP[ch & 1][16 + m][s * 32 + q * 8];
            acc0 = __builtin_amdgcn_mfma_f32_16x16x32_bf16(a0, bcur[s], acc0, 0, 0, 0);
            acc1 = __builtin_amdgcn_mfma_f32_16x16x32_bf16(a1, bcur[s], acc1, 0, 0, 0);
        }

#pragma unroll
        for (int s = 0; s < 8; ++s) bcur[s] = bnxt[s];
    }

    // ---- denominators: thread covered (i_loc, jseg window) across chunks
    pDen[i_loc][tid & 15] = lsum;
    __syncthreads();
    if (tid < 32) {
        float d = 0.f;
#pragma unroll
        for (int k = 0; k < 16; ++k) d += pDen[tid][k];
        denv[tid] = 1.f / d;
    }
    __syncthreads();

    // ---- epilogue: out[row=i][col=d], validated C/D mapping
#pragma unroll
    for (int r = 0; r < 4; ++r) {
        int r0 = q * 4 + r;
        out[(size_t)(rowbase + r0) * HID + dbase + m]      = acc0[r] * denv[r0];
        out[(size_t)(rowbase + 16 + r0) * HID + dbase + m] = acc1[r] * denv[16 + r0];
    }
}

// ---------------------------------------------------------------------------
extern "C" void kernel_launch(void* const* d_in, const int* in_sizes, int n_in,
                              void* d_out, int out_size, void* d_ws, size_t ws_size,
                              hipStream_t stream) {
    const float* X     = (const float*)d_in[0]; // token_embedding [4,2048,512]
    const float* W     = (const float*)d_in[1]; // fc_w [128,512]
    const float* fcb   = (const float*)d_in[2]; // fc_b [128]
    const float* attnw = (const float*)d_in[3]; // attn_w [1,256]
    const float* attnb = (const float*)d_in[4]; // attn_b [1]
    const float* lng   = (const float*)d_in[5]; // ln_g [128]
    const float* lnb   = (const float*)d_in[6]; // ln_b [128]
    float* out = (float*)d_out;                 // h_prime [4,2048,128] fp32

    char* ws = (char*)d_ws;
    unsigned short* hT   = (unsigned short*)ws;                          // 2 MB
    float*          srow = (float*)(ws + 2u * 1024 * 1024);              // 32 KB
    float*          cchd = (float*)(ws + 2u * 1024 * 1024 + 32u * 1024); // 32 KB
    unsigned short* Wb   = (unsigned short*)(ws + 2u * 1024 * 1024 + 64u * 1024); // 128 KB

    k_prep <<<64, 256, 0, stream>>>(W, Wb);
    k_fused<<<NROWS / 16, 512, 0, stream>>>(X, Wb, fcb, attnw, attnb, lng, lnb,
                                            hT, srow, cchd);
    k_attn <<<NROWS / 32, 512, 0, stream>>>(hT, srow, cchd, out);
}

// Round 2
// 104.909 us; speedup vs baseline: 1.0718x; 1.0081x over previous
//
#include <hip/hip_runtime.h>

// Problem constants (GATLayer): B=4, N=2048, TOKEN_DIM=512, HIDDEN=128
// IO dtype: fp32. Internally: bf16 MFMA with fp32 accumulate.
// v9: three dispatches.
//   k_prep : fc_w fp32 -> bf16 (RTNE) once into workspace.
//   k_fused: 32-row blocks x 1024 thr (16 waves; twin waves share Wb slices
//            via L1 -> halves Wb L2 traffic vs 16-row blocks). Same per-wave
//            MFMA/LN/score mappings as validated v8.
//   k_attn : produce-ahead software pipeline -- produce(ch+1) sits in the
//            same barrier region as consume(ch) so exp-VALU overlaps MFMA.
// All fp32->bf16 via manual RTNE f2bf (validated in passing runs).
#define NB      4
#define NTOK    2048
#define TOKDIM  512
#define HID     128
#define NROWS   (NB * NTOK)      // 8192
#define LN_EPS  1e-5f
#define NEG_SLOPE 0.01f

typedef short bf16x8 __attribute__((ext_vector_type(8)));   // 8 bf16 in 4 VGPRs
typedef float f32x4  __attribute__((ext_vector_type(4)));

static __device__ __forceinline__ unsigned short f2bf(float f) {
    union { float f; unsigned int i; } v; v.f = f;
    unsigned int i = v.i;
    i += 0x7FFFu + ((i >> 16) & 1u);   // round-to-nearest-even
    return (unsigned short)(i >> 16);
}

// ---------------------------------------------------------------------------
// k_prep: convert fc_w (128x512 fp32) -> bf16 once. 64 blocks x 256 thr.
// ---------------------------------------------------------------------------
__global__ __launch_bounds__(256) void k_prep(const float* __restrict__ W,
                                              unsigned short* __restrict__ Wb) {
    const int g = blockIdx.x * 256 + threadIdx.x;   // 0..16383
    float4 v = *(const float4*)(W + (size_t)g * 4);
    ushort4 o;
    o.x = f2bf(v.x); o.y = f2bf(v.y); o.z = f2bf(v.z); o.w = f2bf(v.w);
    *(ushort4*)(Wb + (size_t)g * 4) = o;
}

// ---------------------------------------------------------------------------
// k_fused v9: per 32-row tile: FC (MFMA, A from LDS-staged bf16 X, B from
// pre-converted bf16 W) + bias + LayerNorm + scores + transposed hT write.
// Grid 256 blocks x 1024 thr (16 waves). Wave wv: n-cols [(wv&7)*16,+16),
// row-half (wv>>3)*16. Twin waves (wv, wv+8) read identical Wb slices (L1).
// ---------------------------------------------------------------------------
__global__ __launch_bounds__(1024) void k_fused(const float* __restrict__ X,
                                                const unsigned short* __restrict__ Wb,
                                                const float* __restrict__ fcb,
                                                const float* __restrict__ attnw,
                                                const float* __restrict__ attnb,
                                                const float* __restrict__ lng,
                                                const float* __restrict__ lnb,
                                                unsigned short* __restrict__ hT,
                                                float* __restrict__ srow,
                                                float* __restrict__ cc) {
    __shared__ char smem[33280 + 32 * 132 * 4];      // 50176 B
    unsigned short* ldsX = (unsigned short*)smem;    // [32][520]
    unsigned short* ldsT = (unsigned short*)smem;    // [128][36] (reuse, 9216 B)
    float* hfull = (float*)(smem + 33280);           // [32][132]

    const int tid   = threadIdx.x;
    const int wv    = tid >> 6;
    const int lane  = tid & 63;
    const int m     = lane & 15;
    const int q     = lane >> 4;
    const int rowbase = blockIdx.x * 32;
    const int nbase   = (wv & 7) * 16;
    const int rhalf   = (wv >> 3) * 16;              // 0 or 16

    // ---- phase A: stage X tile (32 rows) -> LDS bf16
    {
        const int r  = tid >> 5;            // 0..31
        const int c0 = (tid & 31) * 16;     // 0..496
        const float* xp = X + (size_t)(rowbase + r) * TOKDIM + c0;
        bf16x8 v0, v1;
#pragma unroll
        for (int u = 0; u < 8; ++u) v0[u] = (short)f2bf(xp[u]);
#pragma unroll
        for (int u = 0; u < 8; ++u) v1[u] = (short)f2bf(xp[8 + u]);
        *(bf16x8*)&ldsX[r * 520 + c0]     = v0;
        *(bf16x8*)&ldsX[r * 520 + c0 + 8] = v1;
    }
    __syncthreads();

    // ---- phase B: MFMA. A[m][k] from ldsX (row-half offset), B from bf16 Wb.
    const unsigned short* wp = Wb + (size_t)(nbase + m) * TOKDIM + q * 8;
    f32x4 acc = {0.f, 0.f, 0.f, 0.f};
#pragma unroll
    for (int kk = 0; kk < TOKDIM / 32; ++kk) {
        bf16x8 a = *(const bf16x8*)&ldsX[(rhalf + m) * 520 + kk * 32 + q * 8];
        bf16x8 b = *(const bf16x8*)(wp + kk * 32);
        acc = __builtin_amdgcn_mfma_f32_16x16x32_bf16(a, b, acc, 0, 0, 0);
    }

    // ---- phase C: acc (+fc_b) -> hfull LDS  (validated C/D mapping)
    {
        const float bias = fcb[nbase + m];
#pragma unroll
        for (int r = 0; r < 4; ++r)
            hfull[(rhalf + q * 4 + r) * 132 + nbase + m] = acc[r] + bias;
    }
    __syncthreads();   // hfull ready; ldsX dead (safe to reuse as ldsT)

    // ---- phase D: LN + scores; write bf16 h into ldsT transposed
    {
        const int r   = tid >> 5;           // row 0..31 (one 32-lane group each)
        const int l32 = tid & 31;
        const int c0  = l32 * 4;
        float4 hv = *(const float4*)&hfull[r * 132 + c0];
        float v[4] = {hv.x, hv.y, hv.z, hv.w};

        float s  = v[0] + v[1] + v[2] + v[3];
        float ss = v[0]*v[0] + v[1]*v[1] + v[2]*v[2] + v[3]*v[3];
#pragma unroll
        for (int d = 1; d < 32; d <<= 1) {
            s  += __shfl_xor(s,  d, 64);
            ss += __shfl_xor(ss, d, 64);
        }
        float mu  = s * (1.f / HID);
        float var = ss * (1.f / HID) - mu * mu;
        float rs  = rsqrtf(var + LN_EPS);

        float n[4], sr = 0.f, sc = 0.f;
#pragma unroll
        for (int k = 0; k < 4; ++k) {
            n[k] = lng[c0 + k] * (v[k] - mu) * rs + lnb[c0 + k];
            sr += n[k] * attnw[c0 + k];
            sc += n[k] * attnw[HID + c0 + k];
            ldsT[(c0 + k) * 36 + r] = f2bf(n[k]);
        }
#pragma unroll
        for (int d = 1; d < 32; d <<= 1) {
            sr += __shfl_xor(sr, d, 64);
            sc += __shfl_xor(sc, d, 64);
        }
        if (l32 == 0) {
            int grow = rowbase + r;
            srow[grow] = sr;
            cc[grow]   = sc + attnb[0];
        }
    }
    __syncthreads();

    // ---- phase E: coalesced hT write. thread t: d = t>>3, 4 j's of 32.
    {
        const int d  = tid >> 3;                   // 0..127
        const int j4 = (tid & 7) * 4;              // 0..28
        const int b    = blockIdx.x >> 6;          // 64 blocks per batch
        const int jblk = (blockIdx.x & 63) * 32;
        ushort4 o;
        o.x = ldsT[d * 36 + j4 + 0];
        o.y = ldsT[d * 36 + j4 + 1];
        o.z = ldsT[d * 36 + j4 + 2];
        o.w = ldsT[d * 36 + j4 + 3];
        *(ushort4*)(hT + ((size_t)(b * HID + d)) * NTOK + jblk + j4) = o;
    }
}

// ---------------------------------------------------------------------------
// k_attn v7: 256 blocks x 512 thr (8 waves); block owns 32 i-rows; j in 8
// chunks of 256. Same validated mappings as v6; scheduling change only:
// produce(ch+1) is in the SAME barrier region as consume(ch), so the exp
// VALU work overlaps the MFMA pipe instead of alternating with it.
//  RAW: consume(ch+1) reads pP[(ch+1)&1] after barrier(ch).     -> safe
//  WAR: produce(ch+2) writes pP[ch&1] after barrier(ch+1), and
//       consume(ch) read pP[ch&1] before barrier(ch).           -> safe
// ---------------------------------------------------------------------------
static __device__ __forceinline__ void produce_chunk(
        unsigned short* __restrict__ dst,   // &pP[buf][i_loc][jseg]
        float ci, float4 s0, float4 s1, float4 s2, float4 s3,
        float& lsum) {
    float sv[16] = {s0.x, s0.y, s0.z, s0.w, s1.x, s1.y, s1.z, s1.w,
                    s2.x, s2.y, s2.z, s2.w, s3.x, s3.y, s3.z, s3.w};
    bf16x8 v0, v1;
#pragma unroll
    for (int u = 0; u < 8; ++u) {
        float z = ci + sv[u];
        z = fmaxf(z, NEG_SLOPE * z);
        float p = __expf(z);
        lsum += p;
        v0[u] = (short)f2bf(p);
    }
#pragma unroll
    for (int u = 0; u < 8; ++u) {
        float z = ci + sv[8 + u];
        z = fmaxf(z, NEG_SLOPE * z);
        float p = __expf(z);
        lsum += p;
        v1[u] = (short)f2bf(p);
    }
    *(bf16x8*)dst       = v0;
    *(bf16x8*)(dst + 8) = v1;
}

__global__ __launch_bounds__(512) void k_attn(const unsigned short* __restrict__ hT,
                                              const float* __restrict__ srow,
                                              const float* __restrict__ cc,
                                              float* __restrict__ out) {
    __shared__ unsigned short pP[2][32][264];   // 2 x 16896 B, +8 pad
    __shared__ float pDen[32][16];              // 2 KB
    __shared__ float denv[32];

    const int tid  = threadIdx.x;
    const int wv   = tid >> 6;
    const int lane = tid & 63;
    const int m    = lane & 15;
    const int q    = lane >> 4;
    const int rowbase = blockIdx.x * 32;     // global row base
    const int b    = blockIdx.x >> 6;        // 64 blocks per batch
    const int dbase = wv * 16;

    // producer indices
    const int i_loc = tid >> 4;              // 0..31
    const int jseg  = (tid & 15) * 16;       // 0..240
    const float ci  = cc[rowbase + i_loc];
    const float* sp = srow + (size_t)b * NTOK + jseg;

    // consumer B pointer
    const unsigned short* hp =
        hT + ((size_t)(b * HID + dbase + m)) * NTOK + q * 8;

    f32x4 acc0 = {0.f, 0.f, 0.f, 0.f};      // i-subtile 0 (rows 0..15)
    f32x4 acc1 = {0.f, 0.f, 0.f, 0.f};      // i-subtile 1 (rows 16..31)
    float lsum = 0.f;

    // ---- prefetch srow(0) + B(0); produce chunk 0; prefetch srow(1)
    float4 s0 = *(const float4*)(sp);
    float4 s1 = *(const float4*)(sp + 4);
    float4 s2 = *(const float4*)(sp + 8);
    float4 s3 = *(const float4*)(sp + 12);
    bf16x8 bcur[8], bnxt[8];
#pragma unroll
    for (int s = 0; s < 8; ++s) bcur[s] = *(const bf16x8*)(hp + s * 32);

    produce_chunk(&pP[0][i_loc][jseg], ci, s0, s1, s2, s3, lsum);

    float4 n0, n1, n2, n3;
    {
        const float* spn = sp + 256;
        n0 = *(const float4*)(spn);
        n1 = *(const float4*)(spn + 4);
        n2 = *(const float4*)(spn + 8);
        n3 = *(const float4*)(spn + 12);
    }

    __syncthreads();   // pP[0] ready

#pragma unroll
    for (int ch = 0; ch < 8; ++ch) {
        if (ch < 7) {
            // ---- produce chunk ch+1 (VALU; overlaps MFMA consume below)
            produce_chunk(&pP[(ch + 1) & 1][i_loc][jseg], ci, n0, n1, n2, n3, lsum);

            // ---- prefetch srow(ch+2) for next iteration's produce
            if (ch < 6) {
                const float* spn = sp + (ch + 2) * 256;
                n0 = *(const float4*)(spn);
                n1 = *(const float4*)(spn + 4);
                n2 = *(const float4*)(spn + 8);
                n3 = *(const float4*)(spn + 12);
            }
            // ---- prefetch B(ch+1) for next iteration's consume
            const unsigned short* hpn = hp + (ch + 1) * 256;
#pragma unroll
            for (int s = 0; s < 8; ++s) bnxt[s] = *(const bf16x8*)(hpn + s * 32);
        }

        // ---- consume chunk ch: 8 k-steps, B-frag reused by both i-subtiles
#pragma unroll
        for (int s = 0; s < 8; ++s) {
            bf16x8 a0 = *(const bf16x8*)&pP[ch & 1][m][s * 32 + q * 8];
            bf16x8 a1 = *(const bf16x8*)&pP[ch & 1][16 + m][s * 32 + q * 8];
            acc0 = __builtin_amdgcn_mfma_f32_16x16x32_bf16(a0, bcur[s], acc0, 0, 0, 0);
            acc1 = __builtin_amdgcn_mfma_f32_16x16x32_bf16(a1, bcur[s], acc1, 0, 0, 0);
        }

        __syncthreads();   // pP[(ch+1)&1] complete; consume(ch) drained

#pragma unroll
        for (int s = 0; s < 8; ++s) bcur[s] = bnxt[s];
    }

    // ---- denominators: thread covered (i_loc, jseg window) across chunks
    pDen[i_loc][tid & 15] = lsum;
    __syncthreads();
    if (tid < 32) {
        float d = 0.f;
#pragma unroll
        for (int k = 0; k < 16; ++k) d += pDen[tid][k];
        denv[tid] = 1.f / d;
    }
    __syncthreads();

    // ---- epilogue: out[row=i][col=d], validated C/D mapping
#pragma unroll
    for (int r = 0; r < 4; ++r) {
        int r0 = q * 4 + r;
        out[(size_t)(rowbase + r0) * HID + dbase + m]      = acc0[r] * denv[r0];
        out[(size_t)(rowbase + 16 + r0) * HID + dbase + m] = acc1[r] * denv[16 + r0];
    }
}

// ---------------------------------------------------------------------------
extern "C" void kernel_launch(void* const* d_in, const int* in_sizes, int n_in,
                              void* d_out, int out_size, void* d_ws, size_t ws_size,
                              hipStream_t stream) {
    const float* X     = (const float*)d_in[0]; // token_embedding [4,2048,512]
    const float* W     = (const float*)d_in[1]; // fc_w [128,512]
    const float* fcb   = (const float*)d_in[2]; // fc_b [128]
    const float* attnw = (const float*)d_in[3]; // attn_w [1,256]
    const float* attnb = (const float*)d_in[4]; // attn_b [1]
    const float* lng   = (const float*)d_in[5]; // ln_g [128]
    const float* lnb   = (const float*)d_in[6]; // ln_b [128]
    float* out = (float*)d_out;                 // h_prime [4,2048,128] fp32

    char* ws = (char*)d_ws;
    unsigned short* hT   = (unsigned short*)ws;                          // 2 MB
    float*          srow = (float*)(ws + 2u * 1024 * 1024);              // 32 KB
    float*          cchd = (float*)(ws + 2u * 1024 * 1024 + 32u * 1024); // 32 KB
    unsigned short* Wb   = (unsigned short*)(ws + 2u * 1024 * 1024 + 64u * 1024); // 128 KB

    k_prep <<<64, 256, 0, stream>>>(W, Wb);
    k_fused<<<NROWS / 32, 1024, 0, stream>>>(X, Wb, fcb, attnw, attnb, lng, lnb,
                                             hT, srow, cchd);
    k_attn <<<NROWS / 32, 512, 0, stream>>>(hT, srow, cchd, out);
}